// Round 18
// baseline (241.026 us; speedup 1.0000x reference)
//
#include <hip/hip_runtime.h>

#define DD 4096
#define NROWS 16384
#define EPS 1e-6f

typedef float fx4 __attribute__((ext_vector_type(4)));
typedef int   ix4 __attribute__((ext_vector_type(4)));

// ws: +0 float gmax, +256 float rowmax[16384], +256+64K float rstd[16384].
// Intermediate p = (x+res)*gamma stored as RAW FP32 in d_out (256 MB) --
// exactly the proven-fast write shape (4 x 16B stores/thread, pass2_nb's
// dataflow). pass2 quantizes in place (per-thread exact RAW overlap).

// Pass 1: pass2_nb's exact per-iteration dataflow (3 loads -> compute ->
// one 16B store) + shuffle-reduction tail for rstd/rowmax.
__global__ __launch_bounds__(256) void pass1(
    const float* __restrict__ x, const float* __restrict__ res,
    const float* __restrict__ gamma, float* __restrict__ pout,
    float* __restrict__ rstd, float* __restrict__ rowmax) {
  const int row = blockIdx.x;
  const int t = threadIdx.x;
  const fx4* x4 = (const fx4*)(x + (size_t)row * DD);
  const fx4* r4 = (const fx4*)(res + (size_t)row * DD);
  const fx4* g4 = (const fx4*)gamma;
  fx4* p4 = (fx4*)(pout + (size_t)row * DD);

  float ss = 0.f, mx = 0.f;
#pragma unroll
  for (int i = 0; i < 4; ++i) {
    const int idx = t + i * 256;  // coalesced; same slots as pass2 reads
    fx4 xv = x4[idx], rv = r4[idx], gv = g4[idx];
    fx4 y = xv + rv;
    ss += y.x * y.x + y.y * y.y + y.z * y.z + y.w * y.w;
    fx4 p = y * gv;
    mx = fmaxf(mx, fmaxf(fmaxf(fabsf(p.x), fabsf(p.y)),
                         fmaxf(fabsf(p.z), fabsf(p.w))));
    p4[idx] = p;  // 16B store per iter, 64B/thread: the fast write shape
  }

#pragma unroll
  for (int off = 32; off > 0; off >>= 1) {
    ss += __shfl_down(ss, off, 64);
    mx = fmaxf(mx, __shfl_down(mx, off, 64));
  }
  __shared__ float s_ss[4], s_mx[4];
  const int wave = t >> 6, lane = t & 63;
  if (lane == 0) { s_ss[wave] = ss; s_mx[wave] = mx; }
  __syncthreads();
  if (t == 0) {
    float tss = s_ss[0] + s_ss[1] + s_ss[2] + s_ss[3];
    float tmx = fmaxf(fmaxf(s_mx[0], s_mx[1]), fmaxf(s_mx[2], s_mx[3]));
    float rs = rsqrtf(tss * (1.0f / DD) + EPS);
    rstd[row] = rs;
    rowmax[row] = tmx * rs;  // |normalized output| row max
  }
}

__global__ __launch_bounds__(1024) void reduce_gmax(
    const float* __restrict__ rowmax, float* __restrict__ gmax) {
  const int t = threadIdx.x;
  float m = 0.f;
#pragma unroll
  for (int i = 0; i < NROWS / 1024; ++i) m = fmaxf(m, rowmax[t + i * 1024]);
#pragma unroll
  for (int off = 32; off > 0; off >>= 1) m = fmaxf(m, __shfl_down(m, off, 64));
  __shared__ float s[16];
  if ((t & 63) == 0) s[t >> 6] = m;
  __syncthreads();
  if (t == 0) {
    float r = s[0];
#pragma unroll
    for (int i = 1; i < 16; ++i) r = fmaxf(r, s[i]);
    *gmax = r;
  }
}

// Pass 2: in-place quantize. Thread t reads its own 4 fx4 of p and writes
// int8-valued ix4 to the SAME addresses (per-thread RAW only, per-iteration
// load->store data dependence -> race-free). Math identical to r2 (absmax 1).
__global__ __launch_bounds__(256) void pass2(
    float* __restrict__ pbuf, const float* __restrict__ rstd,
    const float* __restrict__ gmax, int* __restrict__ out) {
  const int row = blockIdx.x;
  const int t = threadIdx.x;
  const float c = rstd[row] * (127.0f / *gmax);
  const fx4* p4 = (const fx4*)(pbuf + (size_t)row * DD);
  ix4* o4 = (ix4*)(out + (size_t)row * DD);
#pragma unroll
  for (int i = 0; i < 4; ++i) {
    const int idx = t + i * 256;
    fx4 p = p4[idx];
    ix4 q;
    q.x = min(max(__float2int_rn(p.x * c), -128), 127);
    q.y = min(max(__float2int_rn(p.y * c), -128), 127);
    q.z = min(max(__float2int_rn(p.z * c), -128), 127);
    q.w = min(max(__float2int_rn(p.w * c), -128), 127);
    o4[idx] = q;  // overwrites exactly the 16B just read
  }
}

// ---- Fallback (ws < 2 MB): recompute path ----
__global__ __launch_bounds__(256) void pass1_nb(
    const float* __restrict__ x, const float* __restrict__ res,
    const float* __restrict__ gamma, float* __restrict__ rstd,
    float* __restrict__ rowmax) {
  const int row = blockIdx.x;
  const int t = threadIdx.x;
  const fx4* x4 = (const fx4*)(x + (size_t)row * DD);
  const fx4* r4 = (const fx4*)(res + (size_t)row * DD);
  const fx4* g4 = (const fx4*)gamma;
  float ss = 0.f, mx = 0.f;
#pragma unroll
  for (int i = 0; i < 4; ++i) {
    const int idx = t + i * 256;
    fx4 y = x4[idx] + r4[idx];
    ss += y.x * y.x + y.y * y.y + y.z * y.z + y.w * y.w;
    fx4 p = y * g4[idx];
    mx = fmaxf(mx, fmaxf(fmaxf(fabsf(p.x), fabsf(p.y)),
                         fmaxf(fabsf(p.z), fabsf(p.w))));
  }
#pragma unroll
  for (int off = 32; off > 0; off >>= 1) {
    ss += __shfl_down(ss, off, 64);
    mx = fmaxf(mx, __shfl_down(mx, off, 64));
  }
  __shared__ float s_ss[4], s_mx[4];
  const int wave = t >> 6, lane = t & 63;
  if (lane == 0) { s_ss[wave] = ss; s_mx[wave] = mx; }
  __syncthreads();
  if (t == 0) {
    float tss = s_ss[0] + s_ss[1] + s_ss[2] + s_ss[3];
    float tmx = fmaxf(fmaxf(s_mx[0], s_mx[1]), fmaxf(s_mx[2], s_mx[3]));
    float rs = rsqrtf(tss * (1.0f / DD) + EPS);
    rstd[row] = rs;
    rowmax[row] = tmx * rs;
  }
}

__global__ __launch_bounds__(256) void pass2_nb(
    const float* __restrict__ x, const float* __restrict__ res,
    const float* __restrict__ gamma, const float* __restrict__ rstd,
    const float* __restrict__ gmax, int* __restrict__ out) {
  const int row = blockIdx.x;
  const int t = threadIdx.x;
  const float c = rstd[row] * (127.0f / *gmax);
  const fx4* x4 = (const fx4*)(x + (size_t)row * DD);
  const fx4* r4 = (const fx4*)(res + (size_t)row * DD);
  const fx4* g4 = (const fx4*)gamma;
  ix4* o4 = (ix4*)(out + (size_t)row * DD);
#pragma unroll
  for (int i = 0; i < 4; ++i) {
    const int idx = t + i * 256;
    fx4 xv = x4[idx], rv = r4[idx], gv = g4[idx];
    ix4 q;
    q.x = min(max(__float2int_rn((xv.x + rv.x) * gv.x * c), -128), 127);
    q.y = min(max(__float2int_rn((xv.y + rv.y) * gv.y * c), -128), 127);
    q.z = min(max(__float2int_rn((xv.z + rv.z) * gv.z * c), -128), 127);
    q.w = min(max(__float2int_rn((xv.w + rv.w) * gv.w * c), -128), 127);
    o4[idx] = q;
  }
}

extern "C" void kernel_launch(void* const* d_in, const int* in_sizes, int n_in,
                              void* d_out, int out_size, void* d_ws, size_t ws_size,
                              hipStream_t stream) {
  const float* x     = (const float*)d_in[0];
  const float* res   = (const float*)d_in[1];
  const float* gamma = (const float*)d_in[2];
  int* out = (int*)d_out;

  char* ws = (char*)d_ws;
  float* gmax   = (float*)ws;
  float* rowmax = (float*)(ws + 256);
  float* rstd   = (float*)(ws + 256 + 64 * 1024);

  if (ws_size >= (size_t)(2 << 20)) {
    float* pbuf = (float*)d_out;  // fp32 intermediate lives in d_out
    pass1<<<NROWS, 256, 0, stream>>>(x, res, gamma, pbuf, rstd, rowmax);
    reduce_gmax<<<1, 1024, 0, stream>>>(rowmax, gmax);
    pass2<<<NROWS, 256, 0, stream>>>(pbuf, rstd, gmax, out);
  } else {
    pass1_nb<<<NROWS, 256, 0, stream>>>(x, res, gamma, rstd, rowmax);
    reduce_gmax<<<1, 1024, 0, stream>>>(rowmax, gmax);
    pass2_nb<<<NROWS, 256, 0, stream>>>(x, res, gamma, rstd, gmax, out);
  }
}

// Round 19
// 191.195 us; speedup vs baseline: 1.2606x; 1.2606x over previous
//
#include <hip/hip_runtime.h>
#include <hip/hip_cooperative_groups.h>

namespace cg = cooperative_groups;

#define DD 4096
#define NROWS 16384
#define EPS 1e-6f
#define RPB 16                  // rows per block (coop kernel)
#define CGRID (NROWS / RPB)     // 1024 blocks = 4/CU on 256 CUs

typedef float fx4 __attribute__((ext_vector_type(4)));
typedef int   ix4 __attribute__((ext_vector_type(4)));

// ============ Single-pass cooperative kernel ============
// Phase A: per block, 16 rows: load x,res -> ss/mx reduce -> quantize
//   p=(x+res)*gamma to row-scaled int8 kept in REGISTERS (q[16][4] uints,
//   static-indexed), rmx[16] = normalized row max. 1 atomicMax per block.
// grid.sync()
// Phase B: gmax via coherent atomic read; rescale registers; stream the
//   256 MB output. Total traffic: 512 MB read + 256 MB write, NOTHING else.
__global__ __launch_bounds__(256, 4) void fused_coop(
    const float* __restrict__ x, const float* __restrict__ res,
    const float* __restrict__ gamma, int* __restrict__ out,
    unsigned int* __restrict__ gmax) {
  const int t = threadIdx.x;
  const int bid = blockIdx.x;
  const fx4* g4 = (const fx4*)gamma;
  __shared__ float s_ss[4], s_mx[4], s_g;

  unsigned int q[RPB][4];   // 64 VGPRs: row-quantized int8, 4/uint
  float rmx[RPB];           // 16 VGPRs: normalized row max
  float bmax = 0.f;

#pragma unroll
  for (int r = 0; r < RPB; ++r) {
    const int row = bid * RPB + r;
    const fx4* x4 = (const fx4*)(x + (size_t)row * DD);
    const fx4* r4 = (const fx4*)(res + (size_t)row * DD);
    fx4 p[4];
    float ss = 0.f, mx = 0.f;
#pragma unroll
    for (int i = 0; i < 4; ++i) {
      const int idx = t + i * 256;  // r4-proven coalesced pattern
      fx4 y = x4[idx] + r4[idx];
      ss += y.x * y.x + y.y * y.y + y.z * y.z + y.w * y.w;
      p[i] = y * g4[idx];
      mx = fmaxf(mx, fmaxf(fmaxf(fabsf(p[i].x), fabsf(p[i].y)),
                           fmaxf(fabsf(p[i].z), fabsf(p[i].w))));
    }
#pragma unroll
    for (int off = 32; off > 0; off >>= 1) {
      ss += __shfl_down(ss, off, 64);
      mx = fmaxf(mx, __shfl_down(mx, off, 64));
    }
    if ((t & 63) == 0) { s_ss[t >> 6] = ss; s_mx[t >> 6] = mx; }
    __syncthreads();
    const float tss = s_ss[0] + s_ss[1] + s_ss[2] + s_ss[3];
    const float tmx = fmaxf(fmaxf(s_mx[0], s_mx[1]), fmaxf(s_mx[2], s_mx[3]));
    __syncthreads();  // s_ss/s_mx reusable next row
    const float rs = rsqrtf(tss * (1.0f / DD) + EPS);
    rmx[r] = tmx * rs;
    bmax = fmaxf(bmax, rmx[r]);
    const float inv = tmx > 0.f ? 127.0f / tmx : 0.f;
#pragma unroll
    for (int i = 0; i < 4; ++i) {
      int a = min(max(__float2int_rn(p[i].x * inv), -127), 127);
      int b = min(max(__float2int_rn(p[i].y * inv), -127), 127);
      int c = min(max(__float2int_rn(p[i].z * inv), -127), 127);
      int e = min(max(__float2int_rn(p[i].w * inv), -127), 127);
      q[r][i] = (unsigned)(a & 255) | ((unsigned)(b & 255) << 8) |
                ((unsigned)(c & 255) << 16) | ((unsigned)(e & 255) << 24);
    }
  }

  // one device-scope atomic per block (1024 total)
  if (t == 0) atomicMax(gmax, __float_as_uint(bmax));

  cg::this_grid().sync();

  // coherent read-back (atomic bypasses any stale per-XCD L2 line)
  if (t == 0) s_g = __uint_as_float(atomicMax(gmax, 0u));
  __syncthreads();
  const float g = s_g;

#pragma unroll
  for (int r = 0; r < RPB; ++r) {
    const int row = bid * RPB + r;
    ix4* orow = (ix4*)(out + (size_t)row * DD);
    const float c = rmx[r] / g;  // <= 1
#pragma unroll
    for (int i = 0; i < 4; ++i) {
      const unsigned w = q[r][i];
      ix4 o;
      o.x = min(max(__float2int_rn((float)((int)(w << 24) >> 24) * c), -128), 127);
      o.y = min(max(__float2int_rn((float)((int)(w << 16) >> 24) * c), -128), 127);
      o.z = min(max(__float2int_rn((float)((int)(w << 8) >> 24) * c), -128), 127);
      o.w = min(max(__float2int_rn((float)((int)w >> 24) * c), -128), 127);
      orow[t + i * 256] = o;  // coalesced 16B output stores
    }
  }
}

// ============ Fallback: proven r14 pipeline (191 us) ============
__global__ __launch_bounds__(256) void pass1(
    const float* __restrict__ x, const float* __restrict__ res,
    const float* __restrict__ gamma, unsigned int* __restrict__ outw,
    float* __restrict__ rowmax) {
  const int row = blockIdx.x;
  const int t = threadIdx.x;
  const fx4* x4 = (const fx4*)(x + (size_t)row * DD);
  const fx4* r4 = (const fx4*)(res + (size_t)row * DD);
  const fx4* g4 = (const fx4*)gamma;

  fx4 p[4];
  float ss = 0.f, mx = 0.f;
#pragma unroll
  for (int i = 0; i < 4; ++i) {
    const int idx = t + i * 256;
    fx4 y = x4[idx] + r4[idx];
    ss += y.x * y.x + y.y * y.y + y.z * y.z + y.w * y.w;
    p[i] = y * g4[idx];
    mx = fmaxf(mx, fmaxf(fmaxf(fabsf(p[i].x), fabsf(p[i].y)),
                         fmaxf(fabsf(p[i].z), fabsf(p[i].w))));
  }
#pragma unroll
  for (int off = 32; off > 0; off >>= 1) {
    ss += __shfl_down(ss, off, 64);
    mx = fmaxf(mx, __shfl_down(mx, off, 64));
  }
  __shared__ float s_ss[4], s_mx[4];
  const int wave = t >> 6, lane = t & 63;
  if (lane == 0) { s_ss[wave] = ss; s_mx[wave] = mx; }
  __syncthreads();
  const float tss = s_ss[0] + s_ss[1] + s_ss[2] + s_ss[3];
  const float tmx = fmaxf(fmaxf(s_mx[0], s_mx[1]), fmaxf(s_mx[2], s_mx[3]));
  const float rs = rsqrtf(tss * (1.0f / DD) + EPS);
  if (t == 0) rowmax[row] = tmx * rs;
  const float inv = tmx > 0.f ? 127.0f / tmx : 0.f;

  ix4 d;
  int* dp = (int*)&d;
#pragma unroll
  for (int i = 0; i < 4; ++i) {
    int a = min(max(__float2int_rn(p[i].x * inv), -127), 127);
    int b = min(max(__float2int_rn(p[i].y * inv), -127), 127);
    int c = min(max(__float2int_rn(p[i].z * inv), -127), 127);
    int e = min(max(__float2int_rn(p[i].w * inv), -127), 127);
    dp[i] = (a & 255) | ((b & 255) << 8) | ((c & 255) << 16) | ((e & 255) << 24);
  }
  *(ix4*)(outw + (size_t)row * DD + 4 * t) = d;
}

__global__ __launch_bounds__(1024) void reduce_gmax(
    const float* __restrict__ rowmax, float* __restrict__ gmaxf) {
  const int t = threadIdx.x;
  float m = 0.f;
#pragma unroll
  for (int i = 0; i < NROWS / 1024; ++i) m = fmaxf(m, rowmax[t + i * 1024]);
#pragma unroll
  for (int off = 32; off > 0; off >>= 1) m = fmaxf(m, __shfl_down(m, off, 64));
  __shared__ float s[16];
  if ((t & 63) == 0) s[t >> 6] = m;
  __syncthreads();
  if (t == 0) {
    float r = s[0];
#pragma unroll
    for (int i = 1; i < 16; ++i) r = fmaxf(r, s[i]);
    *gmaxf = r;
  }
}

__global__ __launch_bounds__(256) void pass2(
    unsigned int* __restrict__ outw, const float* __restrict__ rowmax,
    const float* __restrict__ gmaxf, int* __restrict__ out) {
  const int row = blockIdx.x;
  const int t = threadIdx.x;
  const float c = rowmax[row] / *gmaxf;
  union { ix4 v; unsigned int w[4]; } u;
  u.v = *(const ix4*)(outw + (size_t)row * DD + 4 * t);
  ix4* orow = (ix4*)(out + (size_t)row * DD);
#pragma unroll
  for (int i = 0; i < 4; ++i) {
    const unsigned int w = u.w[i];
    ix4 q;
    q.x = min(max(__float2int_rn((float)((int)(w << 24) >> 24) * c), -128), 127);
    q.y = min(max(__float2int_rn((float)((int)(w << 16) >> 24) * c), -128), 127);
    q.z = min(max(__float2int_rn((float)((int)(w << 8) >> 24) * c), -128), 127);
    q.w = min(max(__float2int_rn((float)((int)w >> 24) * c), -128), 127);
    orow[t + i * 256] = q;
  }
}

extern "C" void kernel_launch(void* const* d_in, const int* in_sizes, int n_in,
                              void* d_out, int out_size, void* d_ws, size_t ws_size,
                              hipStream_t stream) {
  const float* x     = (const float*)d_in[0];
  const float* res   = (const float*)d_in[1];
  const float* gamma = (const float*)d_in[2];
  int* out = (int*)d_out;

  char* ws = (char*)d_ws;
  unsigned int* gmax_u = (unsigned int*)ws;
  float* gmax_f = (float*)ws;
  float* rowmax = (float*)(ws + 256);

  int occ = 0;
  hipOccupancyMaxActiveBlocksPerMultiprocessor(&occ, fused_coop, 256, 0);

  if (occ >= 4 && ws_size >= (size_t)(1 << 20)) {
    // gmax must be re-zeroed every call (atomicMax accumulates)
    hipMemsetAsync(d_ws, 0, 4, stream);
    void* args[] = {(void*)&x, (void*)&res, (void*)&gamma,
                    (void*)&out, (void*)&gmax_u};
    hipLaunchCooperativeKernel((void*)fused_coop, dim3(CGRID), dim3(256),
                               args, 0, stream);
  } else {
    unsigned int* outw = (unsigned int*)d_out;
    pass1<<<NROWS, 256, 0, stream>>>(x, res, gamma, outw, rowmax);
    reduce_gmax<<<1, 1024, 0, stream>>>(rowmax, gmax_f);
    pass2<<<NROWS, 256, 0, stream>>>(outw, rowmax, gmax_f, out);
  }
}